// Round 4
// baseline (330.540 us; speedup 1.0000x reference)
//
#include <hip/hip_runtime.h>

// IoU distance: out[i][j] = inter/union + 1e-16, lhs (N,2), rhs (512,2), out (N,512) fp32.
//
// *** DIAGNOSTIC ROUND ***: identical to R3 kernel except the row sweep runs
// n_passes (=4) times, storing the SAME values each pass (output unchanged,
// deterministic). Purpose: (1) make iou_kernel the longest dispatch so rocprof
// reports its own hbm_gbps / WRITE_SIZE / FETCH_SIZE; (2) dur_us delta vs R3
// gives the marginal cost of streaming the 204.8 MB output. n_passes is a
// runtime arg so the compiler cannot dead-store-eliminate earlier passes.

#define NCOLS 512

typedef float vfloat4 __attribute__((ext_vector_type(4)));

__global__ __launch_bounds__(256) void iou_kernel(
    const float2* __restrict__ lhs,
    const float*  __restrict__ rhs,
    float* __restrict__ out,
    int n_rows, int total_waves, int n_passes)
{
    const int tid  = blockIdx.x * blockDim.x + threadIdx.x;
    const int lane = threadIdx.x & 63;
    const int wave = __builtin_amdgcn_readfirstlane(tid >> 6);

    // Preload this lane's 8 columns of rhs into registers.
    const vfloat4* rhs4 = (const vfloat4*)rhs;
    vfloat4 a0 = rhs4[2 * lane];
    vfloat4 a1 = rhs4[2 * lane + 1];
    vfloat4 b0 = rhs4[128 + 2 * lane];
    vfloat4 b1 = rhs4[128 + 2 * lane + 1];

    float rw[8] = {a0.x, a0.z, a1.x, a1.z, b0.x, b0.z, b1.x, b1.z};
    float rh[8] = {a0.y, a0.w, a1.y, a1.w, b0.y, b0.w, b1.y, b1.w};
    float ra[8];
#pragma unroll
    for (int k = 0; k < 8; ++k) ra[k] = rw[k] * rh[k];

    for (int pass = 0; pass < n_passes; ++pass) {
        for (int row = wave; row < n_rows; row += total_waves) {
            float2 l = lhs[row];
            float la = l.x * l.y;

            float o[8];
#pragma unroll
            for (int k = 0; k < 8; ++k) {
                float inter = fminf(l.x, rw[k]) * fminf(l.y, rh[k]);
                float uni   = (la + ra[k]) - inter;
                o[k] = fmaf(inter, __builtin_amdgcn_rcpf(uni), 1e-16f);
            }

            vfloat4* orow = (vfloat4*)(out + (size_t)row * NCOLS);
            vfloat4 v0 = {o[0], o[1], o[2], o[3]};
            vfloat4 v1 = {o[4], o[5], o[6], o[7]};
            __builtin_nontemporal_store(v0, orow + lane);
            __builtin_nontemporal_store(v1, orow + 64 + lane);
        }
    }
}

extern "C" void kernel_launch(void* const* d_in, const int* in_sizes, int n_in,
                              void* d_out, int out_size, void* d_ws, size_t ws_size,
                              hipStream_t stream) {
    const float2* lhs = (const float2*)d_in[0];
    const float*  rhs = (const float*)d_in[1];
    float* out = (float*)d_out;

    int n_rows = in_sizes[0] / 2;    // 100000

    int blocks = 2048;
    int total_waves = blocks * (256 / 64);
    // n_passes=4: diagnostic multiplier (see header comment).
    iou_kernel<<<blocks, 256, 0, stream>>>(lhs, rhs, out, n_rows, total_waves, 4);
}

// Round 5
// 287.683 us; speedup vs baseline: 1.1490x; 1.1490x over previous
//
#include <hip/hip_runtime.h>

// IoU distance: out[i][j] = inter/union + 1e-16, lhs (N,2), rhs (512,2), out (N,512) fp32.
//
// *** DIAGNOSTIC ROUND 2 (4 passes) ***: R4 showed the store path at 4.59 TB/s
// vs the 6.7 TB/s fill ceiling on the same buffer. Changes vs R4:
//   1. plain float4 stores (drop nontemporal flag — suspect for the BW gap)
//   2. row loop unrolled x4 with batched lhs loads (load-latency MLP)
// Still 4 passes so iou_kernel tops the rocprof table; revert to 1 pass once
// the store path is confirmed at ceiling.

#define NCOLS 512

typedef float vfloat4 __attribute__((ext_vector_type(4)));

__global__ __launch_bounds__(256) void iou_kernel(
    const float2* __restrict__ lhs,
    const float*  __restrict__ rhs,
    float* __restrict__ out,
    int n_rows, int total_waves, int n_passes)
{
    const int lane = threadIdx.x & 63;
    const int wave = __builtin_amdgcn_readfirstlane(
        (blockIdx.x * blockDim.x + threadIdx.x) >> 6);

    // Preload this lane's 8 columns of rhs into registers.
    const vfloat4* rhs4 = (const vfloat4*)rhs;
    vfloat4 a0 = rhs4[2 * lane];
    vfloat4 a1 = rhs4[2 * lane + 1];
    vfloat4 b0 = rhs4[128 + 2 * lane];
    vfloat4 b1 = rhs4[128 + 2 * lane + 1];

    float rw[8] = {a0.x, a0.z, a1.x, a1.z, b0.x, b0.z, b1.x, b1.z};
    float rh[8] = {a0.y, a0.w, a1.y, a1.w, b0.y, b0.w, b1.y, b1.w};
    float ra[8];
#pragma unroll
    for (int k = 0; k < 8; ++k) ra[k] = rw[k] * rh[k];

    for (int pass = 0; pass < n_passes; ++pass) {
        int row = wave;
        // Main loop: 4 rows per iteration, loads batched for MLP.
        for (; row + 3 * total_waves < n_rows; row += 4 * total_waves) {
            float2 l[4];
#pragma unroll
            for (int r = 0; r < 4; ++r) l[r] = lhs[row + r * total_waves];

#pragma unroll
            for (int r = 0; r < 4; ++r) {
                float la = l[r].x * l[r].y;
                float o[8];
#pragma unroll
                for (int k = 0; k < 8; ++k) {
                    float inter = fminf(l[r].x, rw[k]) * fminf(l[r].y, rh[k]);
                    float uni   = (la + ra[k]) - inter;
                    o[k] = fmaf(inter, __builtin_amdgcn_rcpf(uni), 1e-16f);
                }
                vfloat4* orow = (vfloat4*)(out + (size_t)(row + r * total_waves) * NCOLS);
                vfloat4 v0 = {o[0], o[1], o[2], o[3]};
                vfloat4 v1 = {o[4], o[5], o[6], o[7]};
                orow[lane]      = v0;   // cols 0..255   (1 KiB/wave burst)
                orow[64 + lane] = v1;   // cols 256..511 (1 KiB/wave burst)
            }
        }
        // Tail rows.
        for (; row < n_rows; row += total_waves) {
            float2 l = lhs[row];
            float la = l.x * l.y;
            float o[8];
#pragma unroll
            for (int k = 0; k < 8; ++k) {
                float inter = fminf(l.x, rw[k]) * fminf(l.y, rh[k]);
                float uni   = (la + ra[k]) - inter;
                o[k] = fmaf(inter, __builtin_amdgcn_rcpf(uni), 1e-16f);
            }
            vfloat4* orow = (vfloat4*)(out + (size_t)row * NCOLS);
            vfloat4 v0 = {o[0], o[1], o[2], o[3]};
            vfloat4 v1 = {o[4], o[5], o[6], o[7]};
            orow[lane]      = v0;
            orow[64 + lane] = v1;
        }
    }
}

extern "C" void kernel_launch(void* const* d_in, const int* in_sizes, int n_in,
                              void* d_out, int out_size, void* d_ws, size_t ws_size,
                              hipStream_t stream) {
    const float2* lhs = (const float2*)d_in[0];
    const float*  rhs = (const float*)d_in[1];
    float* out = (float*)d_out;

    int n_rows = in_sizes[0] / 2;    // 100000

    int blocks = 2048;
    int total_waves = blocks * (256 / 64);   // 8192 waves, ~12 rows each
    // n_passes=4: diagnostic multiplier (see header comment).
    iou_kernel<<<blocks, 256, 0, stream>>>(lhs, rhs, out, n_rows, total_waves, 4);
}